// Round 6
// baseline (698.273 us; speedup 1.0000x reference)
//
#include <hip/hip_runtime.h>
#include <hip/hip_bf16.h>

typedef __bf16 bf16;
typedef __bf16 bf16x8 __attribute__((ext_vector_type(8)));
typedef float f32x4 __attribute__((ext_vector_type(4)));

#define B_    2
#define L_    2048
#define DM_   2048
#define DI_   4096
#define NST   64
#define PD    64
#define NH    64
#define CONV_ 4224
#define XBCD_ 4288            // CONV_ + NH  (xBC + dt columns)
#define PROJ_ 8384
#define BL_   (B_ * L_)
#define NCHUNK 32             // L_ / 64
#define EPS_  1e-6f

#define WAITV(n) asm volatile("s_waitcnt vmcnt(" #n ")" ::: "memory")
#define LGKM0()  asm volatile("s_waitcnt lgkmcnt(0)" ::: "memory")
#define BAR()    __builtin_amdgcn_s_barrier()
#define SB0()    __builtin_amdgcn_sched_barrier(0)

// ---------------------------------------------------------------- reductions
__device__ __forceinline__ float block_reduce_sum_256(float v) {
  #pragma unroll
  for (int m = 32; m; m >>= 1) v += __shfl_xor(v, m, 64);
  __shared__ float sred[4];
  int w = threadIdx.x >> 6;
  if ((threadIdx.x & 63) == 0) sred[w] = v;
  __syncthreads();
  return sred[0] + sred[1] + sred[2] + sred[3];
}

__device__ __forceinline__ float silu_f(float x) {
  return x / (1.0f + expf(-x));
}

// async global->LDS, 16B per lane. LDS dest is wave-uniform base; HW adds
// lane*16. [m97/m104 semantics]
__device__ __forceinline__ void async16(const bf16* g, bf16* l) {
  __builtin_amdgcn_global_load_lds(
      (__attribute__((address_space(1))) void*)g,
      (__attribute__((address_space(3))) void*)l, 16, 0, 0);
}

// ---------------------------------------------------------------- RMSNorm in
__global__ __launch_bounds__(256) void rmsnorm_in_kernel(
    const float* __restrict__ u, const float* __restrict__ w, bf16* __restrict__ hs) {
  int row = blockIdx.x;
  const float* x = u + (size_t)row * DM_;
  int base = threadIdx.x * 8;
  f32x4 v0 = *(const f32x4*)(x + base);
  f32x4 v1 = *(const f32x4*)(x + base + 4);
  float xv[8], ss = 0.f;
  #pragma unroll
  for (int i = 0; i < 4; i++) { xv[i] = v0[i]; xv[4 + i] = v1[i]; }
  #pragma unroll
  for (int i = 0; i < 8; i++) ss += xv[i] * xv[i];
  ss = block_reduce_sum_256(ss);
  float r = rsqrtf(ss / (float)DM_ + EPS_);
  f32x4 w0 = *(const f32x4*)(w + base);
  f32x4 w1 = *(const f32x4*)(w + base + 4);
  bf16x8 o;
  #pragma unroll
  for (int i = 0; i < 4; i++) { o[i] = (bf16)(w0[i] * xv[i] * r); o[4 + i] = (bf16)(w1[i] * xv[4 + i] * r); }
  *(bf16x8*)(hs + (size_t)row * DM_ + base) = o;
}

// ---------------------------------------------------------------- weight f32->bf16
__global__ __launch_bounds__(256) void convert_w_kernel(
    const float* __restrict__ src, bf16* __restrict__ dst,
    long n_src, long n_dst) {
  long e = ((long)blockIdx.x * 256 + threadIdx.x) * 8;
  if (e >= n_dst) return;
  bf16x8 o;
  if (e < n_src) {
    f32x4 a = *(const f32x4*)(src + e);
    f32x4 b = *(const f32x4*)(src + e + 4);
    #pragma unroll
    for (int q = 0; q < 4; q++) { o[q] = (bf16)a[q]; o[4 + q] = (bf16)b[q]; }
  } else {
    #pragma unroll
    for (int q = 0; q < 8; q++) o[q] = (bf16)0.f;
  }
  *(bf16x8*)(dst + e) = o;
}

// ---------------------------------------------------------------- NT GEMM (m201 8-phase)
// C[M][N] = A[M][K].W[N][K]^T, bf16 in. BK=64, 8 waves (2Mx4N), per-wave
// (BM/2)x(BN/4). Double-buffered LDS; 4 quadrant-phases per K-tile with
// fragment reuse (ds_reads 12/4/8/0); ONE half-tile staged per phase;
// counted vmcnt(GA+2GB) at phase 4 only (3 half-tiles stay in flight —
// never drains in steady state). Slot swizzle: LDS slot s holds global
// slot s^(row&7) (pre-swizzled gload source, XOR'd ds_read).
#define MMQ(MH, NHH, BF) \
  _Pragma("unroll") \
  for (int i_ = 0; i_ < M2; ++i_) { \
    _Pragma("unroll") \
    for (int j_ = 0; j_ < N2; ++j_) { \
      acc[(MH)*M2 + i_][(NHH)*N2 + j_] = __builtin_amdgcn_mfma_f32_16x16x32_bf16( \
          afr[i_][0], BF[j_][0], acc[(MH)*M2 + i_][(NHH)*N2 + j_], 0, 0, 0); \
      acc[(MH)*M2 + i_][(NHH)*N2 + j_] = __builtin_amdgcn_mfma_f32_16x16x32_bf16( \
          afr[i_][1], BF[j_][1], acc[(MH)*M2 + i_][(NHH)*N2 + j_], 0, 0, 0); \
    } \
  }

template <int BM, int BN, bool OUT_F32>
__global__ __launch_bounds__(512, 2) void gemm_nt_8ph(
    const bf16* __restrict__ A, int lda,
    const bf16* __restrict__ W, int ldw,
    void* __restrict__ Cout, int ldc, const float* __restrict__ resid,
    int N, int K) {
  constexpr int WROWS = BM / 2, WCOLS = BN / 4;
  constexpr int MREP = WROWS / 16, NREP = WCOLS / 16;
  constexpr int M2 = MREP / 2, N2 = NREP / 2;
  constexpr int GA = BM / 128, GB = BN / 128;   // gloads per half-tile
  constexpr int NV = GA + 2 * GB;               // steady-state vmcnt
  __shared__ __align__(16) bf16 As[2][BM * 64];
  __shared__ __align__(16) bf16 Bs[2][BN * 64];
  // bijective XCD swizzle (m204)
  int nwg = gridDim.x * gridDim.y;
  int bid = blockIdx.y * gridDim.x + blockIdx.x;
  int q8 = nwg >> 3, r8 = nwg & 7;
  int xcd = bid & 7, loc = bid >> 3;
  int nb = (xcd < r8 ? xcd * (q8 + 1) : r8 * (q8 + 1) + (xcd - r8) * q8) + loc;
  int bn = nb % gridDim.x, bm = nb / gridDim.x;
  int m0 = bm * BM, n0 = bn * BN;
  int tid = threadIdx.x, wave = tid >> 6, lane = tid & 63;
  int wr = wave >> 2, wc = wave & 3;
  int lm = lane & 15, lk = (lane >> 4) * 8;
  int lr = lane >> 3;
  int cse = ((lane & 7) ^ lr) * 8;              // pre-swizzled source slot
  int NT = K / 64;
  f32x4 acc[MREP][NREP] = {};
  bf16x8 afr[M2][2], b0f[N2][2], b1f[N2][2];

  auto stageA = [&](int d, int t, int mh) {     // one A half-tile (GA gloads)
    if (t >= NT) return;
    #pragma unroll
    for (int i = 0; i < GA; ++i) {
      int idx0 = i * 64 + wave * 8;
      int row = (idx0 / (WROWS / 2)) * WROWS + mh * (WROWS / 2) + idx0 % (WROWS / 2);
      async16(A + (size_t)(m0 + row + lr) * lda + t * 64 + cse, &As[d][row * 64]);
    }
  };
  auto stageB = [&](int d, int t, int nh) {     // one B half-tile (GB gloads)
    if (t >= NT) return;
    #pragma unroll
    for (int i = 0; i < GB; ++i) {
      int idx0 = i * 64 + wave * 8;
      int row = (idx0 / (WCOLS / 2)) * WCOLS + nh * (WCOLS / 2) + idx0 % (WCOLS / 2);
      async16(W + (size_t)(n0 + row + lr) * ldw + t * 64 + cse, &Bs[d][row * 64]);
    }
  };
  auto readA = [&](int d, int mh) {
    #pragma unroll
    for (int i = 0; i < M2; ++i) {
      int row = wr * WROWS + mh * (WROWS / 2) + i * 16 + lm;
      #pragma unroll
      for (int k = 0; k < 2; ++k) {
        int col = ((((k * 32 + lk) >> 3) ^ (row & 7)) << 3);
        afr[i][k] = *(const bf16x8*)&As[d][row * 64 + col];
      }
    }
  };
  auto readB = [&](int d, int nh, bf16x8 (&bf)[N2][2]) {
    #pragma unroll
    for (int j = 0; j < N2; ++j) {
      int row = wc * WCOLS + nh * (WCOLS / 2) + j * 16 + lm;
      #pragma unroll
      for (int k = 0; k < 2; ++k) {
        int col = ((((k * 32 + lk) >> 3) ^ (row & 7)) << 3);
        bf[j][k] = *(const bf16x8*)&Bs[d][row * 64 + col];
      }
    }
  };

  // prologue: tile0 fully + tile1 {Ah0,Bh0,Bh1}; tile1.Ah1 comes in ph1.
  stageA(0, 0, 0); stageA(0, 0, 1); stageB(0, 0, 0); stageB(0, 0, 1);
  stageA(1, 1, 0); stageB(1, 1, 0); stageB(1, 1, 1);
  if constexpr (NV == 6) WAITV(6); else WAITV(5);
  BAR();

  for (int tc = 0; tc < NT; ++tc) {
    int d = tc & 1;
    // ---- phase 1: quadrant (0,0); stage other-buf Ah1 (tile tc+1)
    stageA(d ^ 1, tc + 1, 1);
    readA(d, 0); readB(d, 0, b0f);
    SB0(); BAR(); LGKM0(); SB0();
    __builtin_amdgcn_s_setprio(1); MMQ(0, 0, b0f); __builtin_amdgcn_s_setprio(0);
    SB0(); BAR();
    // ---- phase 2: (0,1); stage this-buf Ah0 (tile tc+2)
    stageA(d, tc + 2, 0);
    readB(d, 1, b1f);
    SB0(); BAR(); LGKM0(); SB0();
    __builtin_amdgcn_s_setprio(1); MMQ(0, 1, b1f); __builtin_amdgcn_s_setprio(0);
    SB0(); BAR();
    // ---- phase 3: (1,1); stage this-buf Bh0 (tile tc+2)
    stageB(d, tc + 2, 0);
    readA(d, 1);
    SB0(); BAR(); LGKM0(); SB0();
    __builtin_amdgcn_s_setprio(1); MMQ(1, 1, b1f); __builtin_amdgcn_s_setprio(0);
    SB0(); BAR();
    // ---- phase 4: (1,0); stage this-buf Bh1 (tile tc+2); counted vmcnt
    stageB(d, tc + 2, 1);
    SB0(); BAR();
    __builtin_amdgcn_s_setprio(1); MMQ(1, 0, b0f); __builtin_amdgcn_s_setprio(0);
    SB0();
    if (tc + 2 < NT) { if constexpr (NV == 6) WAITV(6); else WAITV(5); }
    else WAITV(0);
    BAR();
  }
  // ---- epilogue
  int r0 = m0 + wr * WROWS + (lane >> 4) * 4;
  #pragma unroll
  for (int i = 0; i < MREP; ++i) {
    #pragma unroll
    for (int j = 0; j < NREP; ++j) {
      int col = n0 + wc * WCOLS + j * 16 + lm;
      if (col < N) {
        #pragma unroll
        for (int r = 0; r < 4; ++r) {
          int row = r0 + i * 16 + r;
          size_t idx = (size_t)row * ldc + col;
          float v = acc[i][j][r];
          if (resid) v += resid[idx];
          if (OUT_F32) ((float*)Cout)[idx] = v;
          else         ((bf16*)Cout)[idx]  = (bf16)v;
        }
      }
    }
  }
}

// ---------------------------------------------------------------- conv1d+SiLU
__global__ __launch_bounds__(256) void conv_silu_kernel(
    const bf16* __restrict__ xbcdt, const float* __restrict__ cw,
    const float* __restrict__ cb, bf16* __restrict__ xc) {
  int idx = blockIdx.x * 256 + threadIdx.x;
  int nC8 = CONV_ / 8;
  if (idx >= BL_ * nC8) return;
  int c8 = idx % nC8, t = idx / nC8;
  int l = t % L_;
  int c = c8 * 8;
  float acc[8];
  f32x4 bv0 = *(const f32x4*)(cb + c);
  f32x4 bv1 = *(const f32x4*)(cb + c + 4);
  #pragma unroll
  for (int q = 0; q < 4; q++) { acc[q] = bv0[q]; acc[4 + q] = bv1[q]; }
  #pragma unroll
  for (int k = 0; k < 4; k++) {
    int ls = l + k - 3;
    if (ls >= 0) {
      const bf16* xp = xbcdt + (size_t)(t + k - 3) * XBCD_ + c;
      bf16x8 xv = *(const bf16x8*)xp;
      f32x4 wv0 = *(const f32x4*)(cw + k * CONV_ + c);
      f32x4 wv1 = *(const f32x4*)(cw + k * CONV_ + c + 4);
      #pragma unroll
      for (int q = 0; q < 4; q++) { acc[q] += (float)xv[q] * wv0[q]; acc[4 + q] += (float)xv[4 + q] * wv1[q]; }
    }
  }
  bf16x8 o;
  #pragma unroll
  for (int q = 0; q < 8; q++) o[q] = (bf16)silu_f(acc[q]);
  *(bf16x8*)(xc + (size_t)t * CONV_ + c) = o;
}

// ---------------------------------------------------------------- dt (softplus)
__global__ __launch_bounds__(256) void dt_kernel(
    const bf16* __restrict__ xbcdt, const float* __restrict__ dt_bias,
    float* __restrict__ dtH) {
  int idx = blockIdx.x * 256 + threadIdx.x;
  if (idx >= BL_ * NH) return;
  int h = idx & 63, t = idx >> 6;
  float raw = (float)xbcdt[(size_t)t * XBCD_ + CONV_ + h] + dt_bias[h];
  float v = (raw > 20.f) ? raw : log1pf(expf(raw));
  dtH[(size_t)h * BL_ + t] = v;
}

// ---------------------------------------------------------------- scan pass 1 (MFMA SSD)
__global__ __launch_bounds__(256) void scan_chunk_mfma(
    bf16* __restrict__ xc, const float* __restrict__ dtH,
    const float* __restrict__ A_log, const float* __restrict__ Dp,
    bf16* __restrict__ Sc) {
  __shared__ bf16 Bs[64][72];   // B rows s, cols n   (swizzled)
  __shared__ bf16 Cs[64][72];   // C rows t, cols n   (natural)
  __shared__ bf16 Xt[64][72];   // x^T rows p, cols s (swizzled)
  __shared__ bf16 Gh[64][72];   // masked G hi  [t][s], later wB hi [n][s]
  __shared__ bf16 Gl[64][72];   // masked G lo  [t][s], later wB lo [n][s]
  __shared__ float dts[64];
  __shared__ float cum[64];
  __shared__ float wsA[64];
  int bi = blockIdx.x;
  int h = bi & 63, c = (bi >> 6) & 31, b = bi >> 11;
  int tid = threadIdx.x;
  int wave = tid >> 6, lane = tid & 63;
  int lm = lane & 15, lk = (lane >> 4) * 8;
  int cl = lane & 15, rw4 = (lane >> 4) * 4;
  int wt = (wave >> 1) * 32, wq = (wave & 1) * 32;
  size_t rowbase = (size_t)b * L_ + c * 64;
  float aA = expf(A_log[h]);
  #pragma unroll
  for (int i = 0; i < 2; i++) {
    int cc = tid + i * 256;
    int s = cc >> 3, e8 = (cc & 7) * 8;
    const bf16* base = xc + (rowbase + s) * CONV_;
    bf16x8 xv = *(const bf16x8*)(base + h * PD + e8);
    bf16x8 bv = *(const bf16x8*)(base + DI_ + e8);
    bf16x8 cv = *(const bf16x8*)(base + DI_ + NST + e8);
    *(bf16x8*)&Bs[s][e8 ^ (s & 56)] = bv;
    *(bf16x8*)&Cs[s][e8] = cv;
    #pragma unroll
    for (int q = 0; q < 8; q++) Xt[e8 + q][s ^ e8] = xv[q];
  }
  if (tid < 64) dts[tid] = dtH[(size_t)h * BL_ + rowbase + tid];
  __syncthreads();
  if (tid < 64) {
    float v = dts[tid];
    #pragma unroll
    for (int off = 1; off < 64; off <<= 1) {
      float o = __shfl_up(v, off, 64);
      if (tid >= off) v += o;
    }
    cum[tid] = v;
  }
  __syncthreads();
  if (tid < 64) wsA[tid] = expf(-aA * (cum[63] - cum[tid])) * dts[tid];
  f32x4 gacc[2][2] = {};
  #pragma unroll
  for (int ks = 0; ks < 64; ks += 32) {
    bf16x8 af[2], bfr[2];
    #pragma unroll
    for (int i = 0; i < 2; i++) af[i] = *(bf16x8*)&Cs[wt + i * 16 + lm][ks + lk];
    #pragma unroll
    for (int j = 0; j < 2; j++) {
      int S = wq + j * 16 + lm;
      bfr[j] = *(bf16x8*)&Bs[S][(ks + lk) ^ (S & 56)];
    }
    #pragma unroll
    for (int i = 0; i < 2; i++)
      #pragma unroll
      for (int j = 0; j < 2; j++)
        gacc[i][j] = __builtin_amdgcn_mfma_f32_16x16x32_bf16(af[i], bfr[j], gacc[i][j], 0, 0, 0);
  }
  #pragma unroll
  for (int i = 0; i < 2; i++) {
    #pragma unroll
    for (int j = 0; j < 2; j++) {
      #pragma unroll
      for (int r = 0; r < 4; r++) {
        int t = wt + i * 16 + rw4 + r;
        int s = wq + j * 16 + cl;
        float g = 0.f;
        if (s <= t) g = gacc[i][j][r] * expf(-aA * (cum[t] - cum[s])) * dts[s];
        bf16 ghi = (bf16)g;
        Gh[t][s] = ghi;
        Gl[t][s] = (bf16)(g - (float)ghi);
      }
    }
  }
  __syncthreads();
  f32x4 yacc[2][2] = {};
  #pragma unroll
  for (int ks = 0; ks < 64; ks += 32) {
    bf16x8 ah[2], al[2], bx[2];
    #pragma unroll
    for (int i = 0; i < 2; i++) {
      ah[i] = *(bf16x8*)&Gh[wt + i * 16 + lm][ks + lk];
      al[i] = *(bf16x8*)&Gl[wt + i * 16 + lm][ks + lk];
    }
    #pragma unroll
    for (int j = 0; j < 2; j++) {
      int P = wq + j * 16 + lm;
      bx[j] = *(bf16x8*)&Xt[P][(ks + lk) ^ (P & 56)];
    }
    #pragma unroll
    for (int i = 0; i < 2; i++)
      #pragma unroll
      for (int j = 0; j < 2; j++) {
        yacc[i][j] = __builtin_amdgcn_mfma_f32_16x16x32_bf16(ah[i], bx[j], yacc[i][j], 0, 0, 0);
        yacc[i][j] = __builtin_amdgcn_mfma_f32_16x16x32_bf16(al[i], bx[j], yacc[i][j], 0, 0, 0);
      }
  }
  float Dv = Dp[h];
  #pragma unroll
  for (int i = 0; i < 2; i++) {
    #pragma unroll
    for (int j = 0; j < 2; j++) {
      int p = wq + j * 16 + cl;
      #pragma unroll
      for (int r = 0; r < 4; r++) {
        int t = wt + i * 16 + rw4 + r;
        float yv = yacc[i][j][r] + Dv * (float)Xt[p][t ^ (p & 56)];
        xc[(rowbase + t) * CONV_ + h * PD + p] = (bf16)yv;
      }
    }
  }
  __syncthreads();
  #pragma unroll
  for (int i = 0; i < 2; i++) {
    int cc = tid + i * 256;
    int n = cc >> 3, s8 = (cc & 7) * 8;
    bf16x8 vh, vl;
    #pragma unroll
    for (int q = 0; q < 8; q++) {
      int s = s8 + q;
      float wb = (float)Bs[s][n ^ (s & 56)] * wsA[s];
      vh[q] = (bf16)wb;
      vl[q] = (bf16)(wb - (float)vh[q]);
    }
    *(bf16x8*)&Gh[n][s8] = vh;
    *(bf16x8*)&Gl[n][s8] = vl;
  }
  __syncthreads();
  f32x4 sacc[2][2] = {};
  #pragma unroll
  for (int ks = 0; ks < 64; ks += 32) {
    bf16x8 ax[2], bh[2], bl[2];
    #pragma unroll
    for (int i = 0; i < 2; i++) {
      int P = wt + i * 16 + lm;
      ax[i] = *(bf16x8*)&Xt[P][(ks + lk) ^ (P & 56)];
    }
    #pragma unroll
    for (int j = 0; j < 2; j++) {
      bh[j] = *(bf16x8*)&Gh[wq + j * 16 + lm][ks + lk];
      bl[j] = *(bf16x8*)&Gl[wq + j * 16 + lm][ks + lk];
    }
    #pragma unroll
    for (int i = 0; i < 2; i++)
      #pragma unroll
      for (int j = 0; j < 2; j++) {
        sacc[i][j] = __builtin_amdgcn_mfma_f32_16x16x32_bf16(ax[i], bh[j], sacc[i][j], 0, 0, 0);
        sacc[i][j] = __builtin_amdgcn_mfma_f32_16x16x32_bf16(ax[i], bl[j], sacc[i][j], 0, 0, 0);
      }
  }
  bf16* scp = Sc + ((((size_t)b * NCHUNK + c) * NH + h) << 12);
  #pragma unroll
  for (int i = 0; i < 2; i++) {
    #pragma unroll
    for (int j = 0; j < 2; j++) {
      int n = wq + j * 16 + cl;
      #pragma unroll
      for (int r = 0; r < 4; r++) {
        int p = wt + i * 16 + rw4 + r;
        scp[p * 64 + n] = (bf16)sacc[i][j][r];
      }
    }
  }
}

// ---------------------------------------------------------------- scan pass 2
__global__ __launch_bounds__(256) void state_scan_kernel(
    bf16* __restrict__ Sc, const float* __restrict__ dtH,
    const float* __restrict__ A_log) {
  __shared__ float sdts[64];
  int b = blockIdx.x >> 6, h = blockIdx.x & 63;
  int tid = threadIdx.x;
  float aA = expf(A_log[h]);
  float H[16] = {};
  for (int c = 0; c < NCHUNK; c++) {
    if (tid < 64) sdts[tid] = dtH[(size_t)h * BL_ + b * L_ + c * 64 + tid];
    __syncthreads();
    float sum = 0.f;
    #pragma unroll 8
    for (int i = 0; i < 64; i++) sum += sdts[i];
    float Atot = expf(-aA * sum);
    bf16* p = Sc + ((((size_t)b * NCHUNK + c) * NH + h) << 12) + tid * 16;
    bf16x8 s0 = *(bf16x8*)p;
    bf16x8 s1 = *(bf16x8*)(p + 8);
    bf16x8 o0, o1;
    #pragma unroll
    for (int q = 0; q < 8; q++) {
      float n0 = Atot * H[q]     + (float)s0[q];
      float n1 = Atot * H[8 + q] + (float)s1[q];
      o0[q] = (bf16)H[q]; o1[q] = (bf16)H[8 + q];
      H[q] = n0; H[8 + q] = n1;
    }
    *(bf16x8*)p = o0;
    *(bf16x8*)(p + 8) = o1;
    __syncthreads();
  }
}

// ---------------------------------------------------------------- scan pass 3 (MFMA)
__global__ __launch_bounds__(256) void y_inter_mfma(
    bf16* __restrict__ xc, const float* __restrict__ dtH,
    const float* __restrict__ A_log, const bf16* __restrict__ Sc) {
  __shared__ bf16 Cs[64][72];
  __shared__ bf16 Hs[64][72];
  __shared__ float dts[64];
  __shared__ float eA[64];
  int bi = blockIdx.x;
  int h = bi & 63, c = (bi >> 6) & 31, b = bi >> 11;
  int tid = threadIdx.x;
  int wave = tid >> 6, lane = tid & 63;
  int lm = lane & 15, lk = (lane >> 4) * 8;
  int cl = lane & 15, rw4 = (lane >> 4) * 4;
  int wt = (wave >> 1) * 32, wp = (wave & 1) * 32;
  size_t rowbase = (size_t)b * L_ + c * 64;
  float aA = expf(A_log[h]);
  const bf16* scp = Sc + ((((size_t)b * NCHUNK + c) * NH + h) << 12);
  #pragma unroll
  for (int i = 0; i < 2; i++) {
    int cc = tid + i * 256;
    int s = cc >> 3, e8 = (cc & 7) * 8;
    bf16x8 cv = *(const bf16x8*)(xc + (rowbase + s) * CONV_ + DI_ + NST + e8);
    *(bf16x8*)&Cs[s][e8] = cv;
  }
  {
    int p = tid >> 2, n16 = (tid & 3) * 16;
    *(bf16x8*)&Hs[p][n16]     = *(const bf16x8*)(scp + p * 64 + n16);
    *(bf16x8*)&Hs[p][n16 + 8] = *(const bf16x8*)(scp + p * 64 + n16 + 8);
  }
  if (tid < 64) dts[tid] = dtH[(size_t)h * BL_ + rowbase + tid];
  __syncthreads();
  if (tid < 64) {
    float v = dts[tid];
    #pragma unroll
    for (int off = 1; off < 64; off <<= 1) {
      float o = __shfl_up(v, off, 64);
      if (tid >= off) v += o;
    }
    eA[tid] = expf(-aA * v);
  }
  __syncthreads();
  f32x4 acc[2][2] = {};
  #pragma unroll
  for (int ks = 0; ks < 64; ks += 32) {
    bf16x8 af[2], bfr[2];
    #pragma unroll
    for (int i = 0; i < 2; i++) af[i]  = *(bf16x8*)&Cs[wt + i * 16 + lm][ks + lk];
    #pragma unroll
    for (int j = 0; j < 2; j++) bfr[j] = *(bf16x8*)&Hs[wp + j * 16 + lm][ks + lk];
    #pragma unroll
    for (int i = 0; i < 2; i++)
      #pragma unroll
      for (int j = 0; j < 2; j++)
        acc[i][j] = __builtin_amdgcn_mfma_f32_16x16x32_bf16(af[i], bfr[j], acc[i][j], 0, 0, 0);
  }
  #pragma unroll
  for (int i = 0; i < 2; i++) {
    #pragma unroll
    for (int j = 0; j < 2; j++) {
      int p = wp + j * 16 + cl;
      #pragma unroll
      for (int r = 0; r < 4; r++) {
        int t = wt + i * 16 + rw4 + r;
        size_t gi = (rowbase + t) * CONV_ + h * PD + p;
        xc[gi] = (bf16)((float)xc[gi] + eA[t] * acc[i][j][r]);
      }
    }
  }
}

// ---------------------------------------------------------------- gated RMSNorm
__global__ __launch_bounds__(256) void gated_norm_kernel(
    const bf16* __restrict__ xc, bf16* __restrict__ zbuf,
    const float* __restrict__ nw) {
  int t = blockIdx.x;
  int base = threadIdx.x * 16;
  const bf16* yr = xc + (size_t)t * CONV_;
  bf16* zr = zbuf + (size_t)t * DI_;
  float tv[16], ss = 0.f;
  #pragma unroll
  for (int i8 = 0; i8 < 2; i8++) {
    bf16x8 yv = *(const bf16x8*)(yr + base + i8 * 8);
    bf16x8 zv = *(const bf16x8*)(zr + base + i8 * 8);
    #pragma unroll
    for (int q = 0; q < 8; q++) {
      float tt = (float)yv[q] * silu_f((float)zv[q]);
      tv[i8 * 8 + q] = tt;
      ss += tt * tt;
    }
  }
  ss = block_reduce_sum_256(ss);
  float r = rsqrtf(ss / (float)DI_ + EPS_);
  #pragma unroll
  for (int i8 = 0; i8 < 2; i8++) {
    f32x4 w0 = *(const f32x4*)(nw + base + i8 * 8);
    f32x4 w1 = *(const f32x4*)(nw + base + i8 * 8 + 4);
    bf16x8 o;
    #pragma unroll
    for (int q = 0; q < 4; q++) {
      o[q]     = (bf16)(w0[q] * tv[i8 * 8 + q] * r);
      o[4 + q] = (bf16)(w1[q] * tv[i8 * 8 + 4 + q] * r);
    }
    *(bf16x8*)(zr + base + i8 * 8) = o;
  }
}

// ---------------------------------------------------------------- ws diagnostic
__global__ void ws_report_kernel(float* out, float ws_mb) {
  if (blockIdx.x == 0 && threadIdx.x == 0) out[0] = ws_mb;
}

// ---------------------------------------------------------------- launch
extern "C" void kernel_launch(void* const* d_in, const int* in_sizes, int n_in,
                              void* d_out, int out_size, void* d_ws, size_t ws_size,
                              hipStream_t stream) {
  const float* u        = (const float*)d_in[0];
  const float* ln_w     = (const float*)d_in[1];
  const float* in_proj  = (const float*)d_in[2];
  const float* conv_w   = (const float*)d_in[3];
  const float* conv_b   = (const float*)d_in[4];
  const float* dt_bias  = (const float*)d_in[5];
  const float* A_log    = (const float*)d_in[6];
  const float* Dp       = (const float*)d_in[7];
  const float* norm_w   = (const float*)d_in[8];
  const float* out_proj = (const float*)d_in[9];
  float* out = (float*)d_out;

  bf16* hs = (bf16*)d_out;     // scratch inside d_out (dead before final GEMM)

  char* ws = (char*)d_ws;
  size_t off = 0;
  auto alloc = [&](size_t bytes) { char* p = ws + off; off = (off + bytes + 255) & ~(size_t)255; return p; };
  float* dtH  = (float*)alloc((size_t)BL_ * NH * 4);          //  1.05 MB  [h][b*L+t]
  bf16*  wbuf = (bf16*)alloc((size_t)4352 * DM_ * 2);         // 17.8 MB bf16 weight slice
  bf16*  shbuf= (bf16*)alloc((size_t)BL_ * XBCD_ * 2);        // 35.1 MB (xbcdt → Sc → zbuf)
  bf16*  xc   = (bf16*)alloc((size_t)BL_ * CONV_ * 2);        // 34.6 MB
  size_t need = off;                                          // ~88.6 MB

  if (ws_size < need) {
    ws_report_kernel<<<1, 64, 0, stream>>>(out, (float)(ws_size >> 20));
    return;
  }

  bf16* xbcdt = shbuf;          // phase 1: BL x XBCD_
  bf16* Sc    = shbuf;          // phase 2: [b][c][h][64][64] bf16 = 32 MB
  bf16* zbuf  = shbuf;          // phase 3: BL x DI_

  rmsnorm_in_kernel<<<BL_, 256, 0, stream>>>(u, ln_w, hs);

  // GEMM1: zxbcdt tail (xBC + dt), weights padded to 4352 rows.
  {
    long nsrc = (long)XBCD_ * DM_, ndst = (long)4352 * DM_;
    convert_w_kernel<<<(int)(ndst / 8 / 256), 256, 0, stream>>>(
        in_proj + (size_t)DI_ * DM_, wbuf, nsrc, ndst);
    gemm_nt_8ph<256, 256, false><<<dim3(4352 / 256, BL_ / 256), 512, 0, stream>>>(
        hs, DM_, wbuf, DM_, xbcdt, XBCD_, nullptr, XBCD_, DM_);
  }
  conv_silu_kernel<<<(BL_ * (CONV_ / 8) + 255) / 256, 256, 0, stream>>>(
      xbcdt, conv_w, conv_b, xc);
  dt_kernel<<<(BL_ * NH + 255) / 256, 256, 0, stream>>>(
      xbcdt, dt_bias, dtH);
  // chunked SSD scan (xbcdt dead from here; shbuf becomes Sc)
  scan_chunk_mfma<<<B_ * NH * NCHUNK, 256, 0, stream>>>(xc, dtH, A_log, Dp, Sc);
  state_scan_kernel<<<B_ * NH, 256, 0, stream>>>(Sc, dtH, A_log);
  y_inter_mfma<<<B_ * NH * NCHUNK, 256, 0, stream>>>(xc, dtH, A_log, Sc);

  // GEMM2: z part of in_proj (Sc dead; shbuf becomes zbuf)
  {
    long n = (long)DI_ * DM_;
    convert_w_kernel<<<(int)(n / 8 / 256), 256, 0, stream>>>(in_proj, wbuf, n, n);
    gemm_nt_8ph<256, 256, false><<<dim3(DI_ / 256, BL_ / 256), 512, 0, stream>>>(
        hs, DM_, wbuf, DM_, zbuf, DI_, nullptr, DI_, DM_);
  }
  gated_norm_kernel<<<BL_, 256, 0, stream>>>(xc, zbuf, norm_w);

  // GEMM3: out projection + residual. BM=128 keeps the grid at 256 blocks.
  {
    long n = (long)DM_ * DI_;
    convert_w_kernel<<<(int)(n / 8 / 256), 256, 0, stream>>>(out_proj, wbuf, n, n);
    gemm_nt_8ph<128, 256, true><<<dim3(DM_ / 256, BL_ / 128), 512, 0, stream>>>(
        zbuf, DI_, wbuf, DI_, out, DM_, u, DM_, DI_);
  }
}

// Round 7
// 599.227 us; speedup vs baseline: 1.1653x; 1.1653x over previous
//
#include <hip/hip_runtime.h>
#include <hip/hip_bf16.h>

typedef __bf16 bf16;
typedef __bf16 bf16x8 __attribute__((ext_vector_type(8)));
typedef float f32x4 __attribute__((ext_vector_type(4)));

#define B_    2
#define L_    2048
#define DM_   2048
#define DI_   4096
#define NST   64
#define PD    64
#define NH    64
#define CONV_ 4224
#define XBCD_ 4288            // CONV_ + NH  (xBC + dt columns)
#define PROJ_ 8384
#define BL_   (B_ * L_)
#define NCHUNK 32             // L_ / 64
#define EPS_  1e-6f

#define WAITV(n) asm volatile("s_waitcnt vmcnt(" #n ")" ::: "memory")
#define BAR()    __builtin_amdgcn_s_barrier()

// ---------------------------------------------------------------- reductions
__device__ __forceinline__ float block_reduce_sum_256(float v) {
  #pragma unroll
  for (int m = 32; m; m >>= 1) v += __shfl_xor(v, m, 64);
  __shared__ float sred[4];
  int w = threadIdx.x >> 6;
  if ((threadIdx.x & 63) == 0) sred[w] = v;
  __syncthreads();
  return sred[0] + sred[1] + sred[2] + sred[3];
}

__device__ __forceinline__ float silu_f(float x) {
  return x / (1.0f + expf(-x));
}

// async global->LDS, 16B per lane. LDS dest is wave-uniform base; HW adds
// lane*16. [m97/m104 semantics]
__device__ __forceinline__ void async16(const bf16* g, bf16* l) {
  __builtin_amdgcn_global_load_lds(
      (__attribute__((address_space(1))) void*)g,
      (__attribute__((address_space(3))) void*)l, 16, 0, 0);
}

// ---------------------------------------------------------------- RMSNorm in
__global__ __launch_bounds__(256) void rmsnorm_in_kernel(
    const float* __restrict__ u, const float* __restrict__ w, bf16* __restrict__ hs) {
  int row = blockIdx.x;
  const float* x = u + (size_t)row * DM_;
  int base = threadIdx.x * 8;
  f32x4 v0 = *(const f32x4*)(x + base);
  f32x4 v1 = *(const f32x4*)(x + base + 4);
  float xv[8], ss = 0.f;
  #pragma unroll
  for (int i = 0; i < 4; i++) { xv[i] = v0[i]; xv[4 + i] = v1[i]; }
  #pragma unroll
  for (int i = 0; i < 8; i++) ss += xv[i] * xv[i];
  ss = block_reduce_sum_256(ss);
  float r = rsqrtf(ss / (float)DM_ + EPS_);
  f32x4 w0 = *(const f32x4*)(w + base);
  f32x4 w1 = *(const f32x4*)(w + base + 4);
  bf16x8 o;
  #pragma unroll
  for (int i = 0; i < 4; i++) { o[i] = (bf16)(w0[i] * xv[i] * r); o[4 + i] = (bf16)(w1[i] * xv[4 + i] * r); }
  *(bf16x8*)(hs + (size_t)row * DM_ + base) = o;
}

// ---------------------------------------------------------------- weight f32->bf16
__global__ __launch_bounds__(256) void convert_w_kernel(
    const float* __restrict__ src, bf16* __restrict__ dst,
    long n_src, long n_dst) {
  long e = ((long)blockIdx.x * 256 + threadIdx.x) * 8;
  if (e >= n_dst) return;
  bf16x8 o;
  if (e < n_src) {
    f32x4 a = *(const f32x4*)(src + e);
    f32x4 b = *(const f32x4*)(src + e + 4);
    #pragma unroll
    for (int q = 0; q < 4; q++) { o[q] = (bf16)a[q]; o[4 + q] = (bf16)b[q]; }
  } else {
    #pragma unroll
    for (int q = 0; q < 8; q++) o[q] = (bf16)0.f;
  }
  *(bf16x8*)(dst + e) = o;
}

// ---------------------------------------------------------------- NT GEMM (128^2 dbuf + counted vmcnt)
// C[M][N] = A[M][K].W[N][K]^T, bf16 in. 128x128 tile, BK=64, 4 waves (2x2),
// 64 KB LDS -> 2 blocks/CU (inter-block overlap, m114) + counted vmcnt(8)
// (tile t+1's loads stay in flight across both barriers, T4). XOR slot
// swizzle: LDS[row][s] = G[row][s^(row&7)] via pre-swizzled gload source;
// ds_read XORs the same key -> 2-way (free) bank access.
template <bool OUT_F32>
__global__ __launch_bounds__(256, 2) void gemm_nt_db(
    const bf16* __restrict__ A, int lda,
    const bf16* __restrict__ W, int ldw,
    void* __restrict__ Cout, int ldc, const float* __restrict__ resid,
    int N, int K) {
  __shared__ __align__(16) bf16 As[2][128 * 64];
  __shared__ __align__(16) bf16 Bs[2][128 * 64];
  // bijective XCD swizzle (m204)
  int nwg = gridDim.x * gridDim.y;
  int bid = blockIdx.y * gridDim.x + blockIdx.x;
  int q8 = nwg >> 3, r8 = nwg & 7;
  int xcd = bid & 7, loc = bid >> 3;
  int nb = (xcd < r8 ? xcd * (q8 + 1) : r8 * (q8 + 1) + (xcd - r8) * q8) + loc;
  int bn = nb % gridDim.x, bm = nb / gridDim.x;
  int m0 = bm * 128, n0 = bn * 128;
  int tid = threadIdx.x, wave = tid >> 6, lane = tid & 63;
  int wm = (wave >> 1) * 64, wn = (wave & 1) * 64;
  int lm = lane & 15, lk = (lane >> 4) * 8;
  int lr = lane >> 3;                  // row within 8-row chunk
  int cse = ((lane & 7) ^ lr) * 8;     // pre-swizzled source slot
  f32x4 acc[4][4] = {};

  auto stage = [&](int d, int t) {
    #pragma unroll
    for (int i = 0; i < 4; ++i) {
      int row = (wave * 4 + i) * 8;    // 16 chunks of 8 rows; 4 per wave
      async16(A + (size_t)(m0 + row + lr) * lda + t * 64 + cse, &As[d][row * 64]);
      async16(W + (size_t)(n0 + row + lr) * ldw + t * 64 + cse, &Bs[d][row * 64]);
    }
  };

  int NT = K / 64;
  stage(0, 0);                          // 8 outstanding
  for (int t = 0; t < NT; ++t) {
    int d = t & 1;
    if (t + 1 < NT) { stage(d ^ 1, t + 1); WAITV(8); }   // t landed; t+1 in flight
    else            { WAITV(0); }
    BAR();
    #pragma unroll
    for (int ks = 0; ks < 64; ks += 32) {
      bf16x8 af[4], bf[4];
      #pragma unroll
      for (int i = 0; i < 4; ++i) {
        int row = wm + i * 16 + lm;
        af[i] = *(const bf16x8*)&As[d][row * 64 + ((((ks + lk) >> 3) ^ (row & 7)) << 3)];
      }
      #pragma unroll
      for (int j = 0; j < 4; ++j) {
        int row = wn + j * 16 + lm;
        bf[j] = *(const bf16x8*)&Bs[d][row * 64 + ((((ks + lk) >> 3) ^ (row & 7)) << 3)];
      }
      #pragma unroll
      for (int i = 0; i < 4; ++i)
        #pragma unroll
        for (int j = 0; j < 4; ++j)
          acc[i][j] = __builtin_amdgcn_mfma_f32_16x16x32_bf16(af[i], bf[j], acc[i][j], 0, 0, 0);
    }
    BAR();
  }
  // ---- epilogue
  int r0 = m0 + wm + (lane >> 4) * 4;
  #pragma unroll
  for (int i = 0; i < 4; ++i) {
    #pragma unroll
    for (int j = 0; j < 4; ++j) {
      int col = n0 + wn + j * 16 + lm;
      if (col < N) {
        #pragma unroll
        for (int r = 0; r < 4; ++r) {
          int row = r0 + i * 16 + r;
          size_t idx = (size_t)row * ldc + col;
          float v = acc[i][j][r];
          if (resid) v += resid[idx];
          if (OUT_F32) ((float*)Cout)[idx] = v;
          else         ((bf16*)Cout)[idx]  = (bf16)v;
        }
      }
    }
  }
}

// ---------------------------------------------------------------- conv1d+SiLU (B/C cols only)
__global__ __launch_bounds__(256) void conv_bc_kernel(
    const bf16* __restrict__ xbcdt, const float* __restrict__ cw,
    const float* __restrict__ cb, bf16* __restrict__ xc) {
  int idx = blockIdx.x * 256 + threadIdx.x;
  if (idx >= BL_ * 16) return;          // 128 B/C cols / 8
  int c8 = idx & 15, t = idx >> 4;
  int l = t % L_;
  int c = DI_ + c8 * 8;
  float acc[8];
  f32x4 bv0 = *(const f32x4*)(cb + c);
  f32x4 bv1 = *(const f32x4*)(cb + c + 4);
  #pragma unroll
  for (int q = 0; q < 4; q++) { acc[q] = bv0[q]; acc[4 + q] = bv1[q]; }
  #pragma unroll
  for (int k = 0; k < 4; k++) {
    int ls = l + k - 3;
    if (ls >= 0) {
      const bf16* xp = xbcdt + (size_t)(t + k - 3) * XBCD_ + c;
      bf16x8 xv = *(const bf16x8*)xp;
      f32x4 wv0 = *(const f32x4*)(cw + k * CONV_ + c);
      f32x4 wv1 = *(const f32x4*)(cw + k * CONV_ + c + 4);
      #pragma unroll
      for (int q = 0; q < 4; q++) { acc[q] += (float)xv[q] * wv0[q]; acc[4 + q] += (float)xv[4 + q] * wv1[q]; }
    }
  }
  bf16x8 o;
  #pragma unroll
  for (int q = 0; q < 8; q++) o[q] = (bf16)silu_f(acc[q]);
  *(bf16x8*)(xc + (size_t)t * CONV_ + c) = o;
}

// ---------------------------------------------------------------- dt (softplus)
__global__ __launch_bounds__(256) void dt_kernel(
    const bf16* __restrict__ xbcdt, const float* __restrict__ dt_bias,
    float* __restrict__ dtH) {
  int idx = blockIdx.x * 256 + threadIdx.x;
  if (idx >= BL_ * NH) return;
  int h = idx & 63, t = idx >> 6;
  float raw = (float)xbcdt[(size_t)t * XBCD_ + CONV_ + h] + dt_bias[h];
  float v = (raw > 20.f) ? raw : log1pf(expf(raw));
  dtH[(size_t)h * BL_ + t] = v;
}

// ---------------------------------------------------------------- scan pass 1 (MFMA SSD, fused x-conv)
// One block per (b,c,h). Convolves its own 64x64 x-sub-tile in registers
// (bit-identical to the old conv_silu path), stages into Xt, then the SSD
// chunk math. y(+Dx) overwrites the x-region of xc.
__global__ __launch_bounds__(256) void scan_chunk_mfma(
    bf16* __restrict__ xc, const bf16* __restrict__ xbcdt,
    const float* __restrict__ cw, const float* __restrict__ cb,
    const float* __restrict__ dtH,
    const float* __restrict__ A_log, const float* __restrict__ Dp,
    bf16* __restrict__ Sc) {
  __shared__ bf16 Bs[64][72];   // B rows s, cols n   (swizzled)
  __shared__ bf16 Cs[64][72];   // C rows t, cols n   (natural)
  __shared__ bf16 Xt[64][72];   // x^T rows p, cols s (swizzled)
  __shared__ bf16 Gh[64][72];   // masked G hi  [t][s], later wB hi [n][s]
  __shared__ bf16 Gl[64][72];   // masked G lo  [t][s], later wB lo [n][s]
  __shared__ float dts[64];
  __shared__ float cum[64];
  __shared__ float wsA[64];
  int bi = blockIdx.x;
  int h = bi & 63, c = (bi >> 6) & 31, b = bi >> 11;
  int tid = threadIdx.x;
  int wave = tid >> 6, lane = tid & 63;
  int lm = lane & 15, lk = (lane >> 4) * 8;
  int cl = lane & 15, rw4 = (lane >> 4) * 4;
  int wt = (wave >> 1) * 32, wq = (wave & 1) * 32;
  size_t rowbase = (size_t)b * L_ + c * 64;
  float aA = expf(A_log[h]);
  // ---- stage: x via fused conv (registers), B (swizzled), C (natural)
  #pragma unroll
  for (int i = 0; i < 2; i++) {
    int cc = tid + i * 256;
    int s = cc >> 3, e8 = (cc & 7) * 8;
    const bf16* base = xc + (rowbase + s) * CONV_;
    bf16x8 bv = *(const bf16x8*)(base + DI_ + e8);
    bf16x8 cv = *(const bf16x8*)(base + DI_ + NST + e8);
    *(bf16x8*)&Bs[s][e8 ^ (s & 56)] = bv;
    *(bf16x8*)&Cs[s][e8] = cv;
    // fused depthwise conv + SiLU for x columns h*PD + e8 .. +7
    int col = h * PD + e8;
    int l = c * 64 + s;
    float acc[8];
    f32x4 cb0 = *(const f32x4*)(cb + col);
    f32x4 cb1 = *(const f32x4*)(cb + col + 4);
    #pragma unroll
    for (int q = 0; q < 4; q++) { acc[q] = cb0[q]; acc[4 + q] = cb1[q]; }
    #pragma unroll
    for (int k = 0; k < 4; k++) {
      int ls = l + k - 3;
      if (ls >= 0) {
        const bf16* xp = xbcdt + (rowbase + s + k - 3) * XBCD_ + col;
        bf16x8 xv = *(const bf16x8*)xp;
        f32x4 wv0 = *(const f32x4*)(cw + k * CONV_ + col);
        f32x4 wv1 = *(const f32x4*)(cw + k * CONV_ + col + 4);
        #pragma unroll
        for (int q = 0; q < 4; q++) { acc[q] += (float)xv[q] * wv0[q]; acc[4 + q] += (float)xv[4 + q] * wv1[q]; }
      }
    }
    #pragma unroll
    for (int q = 0; q < 8; q++) Xt[e8 + q][s ^ e8] = (bf16)silu_f(acc[q]);
  }
  if (tid < 64) dts[tid] = dtH[(size_t)h * BL_ + rowbase + tid];
  __syncthreads();
  // ---- inclusive prefix sum of dt (wave 0)
  if (tid < 64) {
    float v = dts[tid];
    #pragma unroll
    for (int off = 1; off < 64; off <<= 1) {
      float o = __shfl_up(v, off, 64);
      if (tid >= off) v += o;
    }
    cum[tid] = v;
  }
  __syncthreads();
  if (tid < 64) wsA[tid] = expf(-aA * (cum[63] - cum[tid])) * dts[tid];
  // ---- G[t][s] = sum_n C[t][n] * B[s][n]
  f32x4 gacc[2][2] = {};
  #pragma unroll
  for (int ks = 0; ks < 64; ks += 32) {
    bf16x8 af[2], bfr[2];
    #pragma unroll
    for (int i = 0; i < 2; i++) af[i] = *(bf16x8*)&Cs[wt + i * 16 + lm][ks + lk];
    #pragma unroll
    for (int j = 0; j < 2; j++) {
      int S = wq + j * 16 + lm;
      bfr[j] = *(bf16x8*)&Bs[S][(ks + lk) ^ (S & 56)];
    }
    #pragma unroll
    for (int i = 0; i < 2; i++)
      #pragma unroll
      for (int j = 0; j < 2; j++)
        gacc[i][j] = __builtin_amdgcn_mfma_f32_16x16x32_bf16(af[i], bfr[j], gacc[i][j], 0, 0, 0);
  }
  // ---- causal decay mask, hi/lo split -> Gh/Gl [t][s]
  #pragma unroll
  for (int i = 0; i < 2; i++) {
    #pragma unroll
    for (int j = 0; j < 2; j++) {
      #pragma unroll
      for (int r = 0; r < 4; r++) {
        int t = wt + i * 16 + rw4 + r;
        int s = wq + j * 16 + cl;
        float g = 0.f;
        if (s <= t) g = gacc[i][j][r] * expf(-aA * (cum[t] - cum[s])) * dts[s];
        bf16 ghi = (bf16)g;
        Gh[t][s] = ghi;
        Gl[t][s] = (bf16)(g - (float)ghi);
      }
    }
  }
  __syncthreads();
  // ---- Y[t][p] = sum_s Gm[t][s] * x_s[p];  + D*x; write into xc x-region
  f32x4 yacc[2][2] = {};
  #pragma unroll
  for (int ks = 0; ks < 64; ks += 32) {
    bf16x8 ah[2], al[2], bx[2];
    #pragma unroll
    for (int i = 0; i < 2; i++) {
      ah[i] = *(bf16x8*)&Gh[wt + i * 16 + lm][ks + lk];
      al[i] = *(bf16x8*)&Gl[wt + i * 16 + lm][ks + lk];
    }
    #pragma unroll
    for (int j = 0; j < 2; j++) {
      int P = wq + j * 16 + lm;
      bx[j] = *(bf16x8*)&Xt[P][(ks + lk) ^ (P & 56)];
    }
    #pragma unroll
    for (int i = 0; i < 2; i++)
      #pragma unroll
      for (int j = 0; j < 2; j++) {
        yacc[i][j] = __builtin_amdgcn_mfma_f32_16x16x32_bf16(ah[i], bx[j], yacc[i][j], 0, 0, 0);
        yacc[i][j] = __builtin_amdgcn_mfma_f32_16x16x32_bf16(al[i], bx[j], yacc[i][j], 0, 0, 0);
      }
  }
  float Dv = Dp[h];
  #pragma unroll
  for (int i = 0; i < 2; i++) {
    #pragma unroll
    for (int j = 0; j < 2; j++) {
      int p = wq + j * 16 + cl;
      #pragma unroll
      for (int r = 0; r < 4; r++) {
        int t = wt + i * 16 + rw4 + r;
        float yv = yacc[i][j][r] + Dv * (float)Xt[p][t ^ (p & 56)];
        xc[(rowbase + t) * CONV_ + h * PD + p] = (bf16)yv;
      }
    }
  }
  __syncthreads();
  // ---- wB[n][s] = w_s * B_s[n], hi/lo into Gh/Gl (reuse buffers)
  #pragma unroll
  for (int i = 0; i < 2; i++) {
    int cc = tid + i * 256;
    int n = cc >> 3, s8 = (cc & 7) * 8;
    bf16x8 vh, vl;
    #pragma unroll
    for (int q = 0; q < 8; q++) {
      int s = s8 + q;
      float wb = (float)Bs[s][n ^ (s & 56)] * wsA[s];
      vh[q] = (bf16)wb;
      vl[q] = (bf16)(wb - (float)vh[q]);
    }
    *(bf16x8*)&Gh[n][s8] = vh;
    *(bf16x8*)&Gl[n][s8] = vl;
  }
  __syncthreads();
  // ---- S[p][n] = sum_s x_s[p] * wB[n][s]; write Sc
  f32x4 sacc[2][2] = {};
  #pragma unroll
  for (int ks = 0; ks < 64; ks += 32) {
    bf16x8 ax[2], bh[2], bl[2];
    #pragma unroll
    for (int i = 0; i < 2; i++) {
      int P = wt + i * 16 + lm;
      ax[i] = *(bf16x8*)&Xt[P][(ks + lk) ^ (P & 56)];
    }
    #pragma unroll
    for (int j = 0; j < 2; j++) {
      bh[j] = *(bf16x8*)&Gh[wq + j * 16 + lm][ks + lk];
      bl[j] = *(bf16x8*)&Gl[wq + j * 16 + lm][ks + lk];
    }
    #pragma unroll
    for (int i = 0; i < 2; i++)
      #pragma unroll
      for (int j = 0; j < 2; j++) {
        sacc[i][j] = __builtin_amdgcn_mfma_f32_16x16x32_bf16(ax[i], bh[j], sacc[i][j], 0, 0, 0);
        sacc[i][j] = __builtin_amdgcn_mfma_f32_16x16x32_bf16(ax[i], bl[j], sacc[i][j], 0, 0, 0);
      }
  }
  bf16* scp = Sc + ((((size_t)b * NCHUNK + c) * NH + h) << 12);
  #pragma unroll
  for (int i = 0; i < 2; i++) {
    #pragma unroll
    for (int j = 0; j < 2; j++) {
      int n = wq + j * 16 + cl;
      #pragma unroll
      for (int r = 0; r < 4; r++) {
        int p = wt + i * 16 + rw4 + r;
        scp[p * 64 + n] = (bf16)sacc[i][j][r];
      }
    }
  }
}

// ---------------------------------------------------------------- scan pass 2
__global__ __launch_bounds__(256) void state_scan_kernel(
    bf16* __restrict__ Sc, const float* __restrict__ dtH,
    const float* __restrict__ A_log) {
  __shared__ float sdts[64];
  int b = blockIdx.x >> 6, h = blockIdx.x & 63;
  int tid = threadIdx.x;
  float aA = expf(A_log[h]);
  float H[16] = {};
  for (int c = 0; c < NCHUNK; c++) {
    if (tid < 64) sdts[tid] = dtH[(size_t)h * BL_ + b * L_ + c * 64 + tid];
    __syncthreads();
    float sum = 0.f;
    #pragma unroll 8
    for (int i = 0; i < 64; i++) sum += sdts[i];
    float Atot = expf(-aA * sum);
    bf16* p = Sc + ((((size_t)b * NCHUNK + c) * NH + h) << 12) + tid * 16;
    bf16x8 s0 = *(bf16x8*)p;
    bf16x8 s1 = *(bf16x8*)(p + 8);
    bf16x8 o0, o1;
    #pragma unroll
    for (int q = 0; q < 8; q++) {
      float n0 = Atot * H[q]     + (float)s0[q];
      float n1 = Atot * H[8 + q] + (float)s1[q];
      o0[q] = (bf16)H[q]; o1[q] = (bf16)H[8 + q];
      H[q] = n0; H[8 + q] = n1;
    }
    *(bf16x8*)p = o0;
    *(bf16x8*)(p + 8) = o1;
    __syncthreads();
  }
}

// ---------------------------------------------------------------- scan pass 3 (MFMA)
__global__ __launch_bounds__(256) void y_inter_mfma(
    bf16* __restrict__ xc, const float* __restrict__ dtH,
    const float* __restrict__ A_log, const bf16* __restrict__ Sc) {
  __shared__ bf16 Cs[64][72];
  __shared__ bf16 Hs[64][72];
  __shared__ float dts[64];
  __shared__ float eA[64];
  int bi = blockIdx.x;
  int h = bi & 63, c = (bi >> 6) & 31, b = bi >> 11;
  int tid = threadIdx.x;
  int wave = tid >> 6, lane = tid & 63;
  int lm = lane & 15, lk = (lane >> 4) * 8;
  int cl = lane & 15, rw4 = (lane >> 4) * 4;
  int wt = (wave >> 1) * 32, wp = (wave & 1) * 32;
  size_t rowbase = (size_t)b * L_ + c * 64;
  float aA = expf(A_log[h]);
  const bf16* scp = Sc + ((((size_t)b * NCHUNK + c) * NH + h) << 12);
  #pragma unroll
  for (int i = 0; i < 2; i++) {
    int cc = tid + i * 256;
    int s = cc >> 3, e8 = (cc & 7) * 8;
    bf16x8 cv = *(const bf16x8*)(xc + (rowbase + s) * CONV_ + DI_ + NST + e8);
    *(bf16x8*)&Cs[s][e8] = cv;
  }
  {
    int p = tid >> 2, n16 = (tid & 3) * 16;
    *(bf16x8*)&Hs[p][n16]     = *(const bf16x8*)(scp + p * 64 + n16);
    *(bf16x8*)&Hs[p][n16 + 8] = *(const bf16x8*)(scp + p * 64 + n16 + 8);
  }
  if (tid < 64) dts[tid] = dtH[(size_t)h * BL_ + rowbase + tid];
  __syncthreads();
  if (tid < 64) {
    float v = dts[tid];
    #pragma unroll
    for (int off = 1; off < 64; off <<= 1) {
      float o = __shfl_up(v, off, 64);
      if (tid >= off) v += o;
    }
    eA[tid] = expf(-aA * v);
  }
  __syncthreads();
  f32x4 acc[2][2] = {};
  #pragma unroll
  for (int ks = 0; ks < 64; ks += 32) {
    bf16x8 af[2], bfr[2];
    #pragma unroll
    for (int i = 0; i < 2; i++) af[i]  = *(bf16x8*)&Cs[wt + i * 16 + lm][ks + lk];
    #pragma unroll
    for (int j = 0; j < 2; j++) bfr[j] = *(bf16x8*)&Hs[wp + j * 16 + lm][ks + lk];
    #pragma unroll
    for (int i = 0; i < 2; i++)
      #pragma unroll
      for (int j = 0; j < 2; j++)
        acc[i][j] = __builtin_amdgcn_mfma_f32_16x16x32_bf16(af[i], bfr[j], acc[i][j], 0, 0, 0);
  }
  #pragma unroll
  for (int i = 0; i < 2; i++) {
    #pragma unroll
    for (int j = 0; j < 2; j++) {
      int p = wp + j * 16 + cl;
      #pragma unroll
      for (int r = 0; r < 4; r++) {
        int t = wt + i * 16 + rw4 + r;
        size_t gi = (rowbase + t) * CONV_ + h * PD + p;
        xc[gi] = (bf16)((float)xc[gi] + eA[t] * acc[i][j][r]);
      }
    }
  }
}

// ---------------------------------------------------------------- gated RMSNorm
__global__ __launch_bounds__(256) void gated_norm_kernel(
    const bf16* __restrict__ xc, bf16* __restrict__ zbuf,
    const float* __restrict__ nw) {
  int t = blockIdx.x;
  int base = threadIdx.x * 16;
  const bf16* yr = xc + (size_t)t * CONV_;
  bf16* zr = zbuf + (size_t)t * DI_;
  float tv[16], ss = 0.f;
  #pragma unroll
  for (int i8 = 0; i8 < 2; i8++) {
    bf16x8 yv = *(const bf16x8*)(yr + base + i8 * 8);
    bf16x8 zv = *(const bf16x8*)(zr + base + i8 * 8);
    #pragma unroll
    for (int q = 0; q < 8; q++) {
      float tt = (float)yv[q] * silu_f((float)zv[q]);
      tv[i8 * 8 + q] = tt;
      ss += tt * tt;
    }
  }
  ss = block_reduce_sum_256(ss);
  float r = rsqrtf(ss / (float)DI_ + EPS_);
  #pragma unroll
  for (int i8 = 0; i8 < 2; i8++) {
    f32x4 w0 = *(const f32x4*)(nw + base + i8 * 8);
    f32x4 w1 = *(const f32x4*)(nw + base + i8 * 8 + 4);
    bf16x8 o;
    #pragma unroll
    for (int q = 0; q < 4; q++) {
      o[q]     = (bf16)(w0[q] * tv[i8 * 8 + q] * r);
      o[4 + q] = (bf16)(w1[q] * tv[i8 * 8 + 4 + q] * r);
    }
    *(bf16x8*)(zr + base + i8 * 8) = o;
  }
}

// ---------------------------------------------------------------- ws diagnostic
__global__ void ws_report_kernel(float* out, float ws_mb) {
  if (blockIdx.x == 0 && threadIdx.x == 0) out[0] = ws_mb;
}

// ---------------------------------------------------------------- launch
extern "C" void kernel_launch(void* const* d_in, const int* in_sizes, int n_in,
                              void* d_out, int out_size, void* d_ws, size_t ws_size,
                              hipStream_t stream) {
  const float* u        = (const float*)d_in[0];
  const float* ln_w     = (const float*)d_in[1];
  const float* in_proj  = (const float*)d_in[2];
  const float* conv_w   = (const float*)d_in[3];
  const float* conv_b   = (const float*)d_in[4];
  const float* dt_bias  = (const float*)d_in[5];
  const float* A_log    = (const float*)d_in[6];
  const float* Dp       = (const float*)d_in[7];
  const float* norm_w   = (const float*)d_in[8];
  const float* out_proj = (const float*)d_in[9];
  float* out = (float*)d_out;

  bf16* hs = (bf16*)d_out;     // scratch inside d_out (dead before final GEMM)

  char* ws = (char*)d_ws;
  size_t off = 0;
  auto alloc = [&](size_t bytes) { char* p = ws + off; off = (off + bytes + 255) & ~(size_t)255; return p; };
  float* dtH  = (float*)alloc((size_t)BL_ * NH * 4);          //  1.05 MB  [h][b*L+t]
  bf16*  wbuf = (bf16*)alloc((size_t)4352 * DM_ * 2);         // 17.8 MB bf16 weight slice
  bf16*  shbuf= (bf16*)alloc((size_t)BL_ * XBCD_ * 2);        // 35.1 MB (xbcdt → Sc → zbuf)
  bf16*  xc   = (bf16*)alloc((size_t)BL_ * CONV_ * 2);        // 34.6 MB
  size_t need = off;                                          // ~88.6 MB

  if (ws_size < need) {
    ws_report_kernel<<<1, 64, 0, stream>>>(out, (float)(ws_size >> 20));
    return;
  }

  bf16* xbcdt = shbuf;          // phase 1: BL x XBCD_  (kept live through scan pass 1)
  bf16* zbuf  = shbuf;          // phase 3: BL x DI_
  // Sc lives in xc? no — Sc must coexist with xbcdt (scan reads xbcdt for conv).
  // Use the tail of ws: Sc = 32 MB after xc.
  bf16* Sc = (bf16*)alloc((size_t)B_ * NCHUNK * NH * 64 * 64 * 2);   // 32 MB
  need = off;
  if (ws_size < need) {
    ws_report_kernel<<<1, 64, 0, stream>>>(out, (float)(ws_size >> 20));
    return;
  }

  rmsnorm_in_kernel<<<BL_, 256, 0, stream>>>(u, ln_w, hs);

  // GEMM1: zxbcdt tail (xBC + dt), weights padded to 4352 rows.
  {
    long nsrc = (long)XBCD_ * DM_, ndst = (long)4352 * DM_;
    convert_w_kernel<<<(int)(ndst / 8 / 256), 256, 0, stream>>>(
        in_proj + (size_t)DI_ * DM_, wbuf, nsrc, ndst);
    gemm_nt_db<false><<<dim3(4352 / 128, BL_ / 128), 256, 0, stream>>>(
        hs, DM_, wbuf, DM_, xbcdt, XBCD_, nullptr, XBCD_, DM_);
  }
  conv_bc_kernel<<<(BL_ * 16 + 255) / 256, 256, 0, stream>>>(
      xbcdt, conv_w, conv_b, xc);
  dt_kernel<<<(BL_ * NH + 255) / 256, 256, 0, stream>>>(
      xbcdt, dt_bias, dtH);
  // chunked SSD scan with fused x-conv (xbcdt still live)
  scan_chunk_mfma<<<B_ * NH * NCHUNK, 256, 0, stream>>>(
      xc, xbcdt, conv_w, conv_b, dtH, A_log, Dp, Sc);
  state_scan_kernel<<<B_ * NH, 256, 0, stream>>>(Sc, dtH, A_log);
  y_inter_mfma<<<B_ * NH * NCHUNK, 256, 0, stream>>>(xc, dtH, A_log, Sc);

  // GEMM2: z part of in_proj (xbcdt dead; shbuf becomes zbuf)
  {
    long n = (long)DI_ * DM_;
    convert_w_kernel<<<(int)(n / 8 / 256), 256, 0, stream>>>(in_proj, wbuf, n, n);
    gemm_nt_db<false><<<dim3(DI_ / 128, BL_ / 128), 256, 0, stream>>>(
        hs, DM_, wbuf, DM_, zbuf, DI_, nullptr, DI_, DM_);
  }
  gated_norm_kernel<<<BL_, 256, 0, stream>>>(xc, zbuf, norm_w);

  // GEMM3: out projection + residual
  {
    long n = (long)DM_ * DI_;
    convert_w_kernel<<<(int)(n / 8 / 256), 256, 0, stream>>>(out_proj, wbuf, n, n);
    gemm_nt_db<true><<<dim3(DM_ / 128, BL_ / 128), 256, 0, stream>>>(
        zbuf, DI_, wbuf, DI_, out, DM_, u, DM_, DI_);
  }
}

// Round 8
// 544.747 us; speedup vs baseline: 1.2818x; 1.1000x over previous
//
#include <hip/hip_runtime.h>
#include <hip/hip_bf16.h>

typedef __bf16 bf16;
typedef __bf16 bf16x8 __attribute__((ext_vector_type(8)));
typedef float f32x4 __attribute__((ext_vector_type(4)));

#define B_    2
#define L_    2048
#define DM_   2048
#define DI_   4096
#define NST   64
#define PD    64
#define NH    64
#define CONV_ 4224
#define XBCD_ 4288            // CONV_ + NH  (xBC + dt columns)
#define PROJ_ 8384
#define BL_   (B_ * L_)
#define NCHUNK 32             // L_ / 64
#define EPS_  1e-6f

#define WAITV(n) asm volatile("s_waitcnt vmcnt(" #n ")" ::: "memory")
#define BAR()    __builtin_amdgcn_s_barrier()

// ---------------------------------------------------------------- reductions
__device__ __forceinline__ float block_reduce_sum_256(float v) {
  #pragma unroll
  for (int m = 32; m; m >>= 1) v += __shfl_xor(v, m, 64);
  __shared__ float sred[4];
  int w = threadIdx.x >> 6;
  if ((threadIdx.x & 63) == 0) sred[w] = v;
  __syncthreads();
  return sred[0] + sred[1] + sred[2] + sred[3];
}

__device__ __forceinline__ float silu_f(float x) {
  return x / (1.0f + expf(-x));
}

// async global->LDS, 16B per lane. LDS dest is wave-uniform base; HW adds
// lane*16. [m97/m104 semantics]
__device__ __forceinline__ void async16(const bf16* g, bf16* l) {
  __builtin_amdgcn_global_load_lds(
      (__attribute__((address_space(1))) void*)g,
      (__attribute__((address_space(3))) void*)l, 16, 0, 0);
}

// ---------------------------------------------------------------- RMSNorm in
__global__ __launch_bounds__(256) void rmsnorm_in_kernel(
    const float* __restrict__ u, const float* __restrict__ w, bf16* __restrict__ hs) {
  int row = blockIdx.x;
  const float* x = u + (size_t)row * DM_;
  int base = threadIdx.x * 8;
  f32x4 v0 = *(const f32x4*)(x + base);
  f32x4 v1 = *(const f32x4*)(x + base + 4);
  float xv[8], ss = 0.f;
  #pragma unroll
  for (int i = 0; i < 4; i++) { xv[i] = v0[i]; xv[4 + i] = v1[i]; }
  #pragma unroll
  for (int i = 0; i < 8; i++) ss += xv[i] * xv[i];
  ss = block_reduce_sum_256(ss);
  float r = rsqrtf(ss / (float)DM_ + EPS_);
  f32x4 w0 = *(const f32x4*)(w + base);
  f32x4 w1 = *(const f32x4*)(w + base + 4);
  bf16x8 o;
  #pragma unroll
  for (int i = 0; i < 4; i++) { o[i] = (bf16)(w0[i] * xv[i] * r); o[4 + i] = (bf16)(w1[i] * xv[4 + i] * r); }
  *(bf16x8*)(hs + (size_t)row * DM_ + base) = o;
}

// ---------------------------------------------------------------- weight f32->bf16
__global__ __launch_bounds__(256) void convert_w_kernel(
    const float* __restrict__ src, bf16* __restrict__ dst,
    long n_src, long n_dst) {
  long e = ((long)blockIdx.x * 256 + threadIdx.x) * 8;
  if (e >= n_dst) return;
  bf16x8 o;
  if (e < n_src) {
    f32x4 a = *(const f32x4*)(src + e);
    f32x4 b = *(const f32x4*)(src + e + 4);
    #pragma unroll
    for (int q = 0; q < 4; q++) { o[q] = (bf16)a[q]; o[4 + q] = (bf16)b[q]; }
  } else {
    #pragma unroll
    for (int q = 0; q < 8; q++) o[q] = (bf16)0.f;
  }
  *(bf16x8*)(dst + e) = o;
}

// ---------------------------------------------------------------- NT GEMM (m97 single-buffer + swizzle)
// C[M][N] = A[M][K].W[N][K]^T, bf16 in. 128x128 tile, BK=64, 4 waves (2x2),
// 32 KB LDS -> up to 5 blocks/CU (inter-block overlap absorbs the drain,
// m114/m97). XOR slot swizzle: LDS[row][s] = G[row][s^(row&7)] via
// pre-swizzled gload source; ds_read XORs the same key -> conflict-free.
template <bool OUT_F32>
__global__ __launch_bounds__(256, 4) void gemm_nt_sb(
    const bf16* __restrict__ A, int lda,
    const bf16* __restrict__ W, int ldw,
    void* __restrict__ Cout, int ldc, const float* __restrict__ resid,
    int N, int K) {
  __shared__ __align__(16) bf16 As[128 * 64];
  __shared__ __align__(16) bf16 Bs[128 * 64];
  // bijective XCD swizzle (m204)
  int nwg = gridDim.x * gridDim.y;
  int bid = blockIdx.y * gridDim.x + blockIdx.x;
  int q8 = nwg >> 3, r8 = nwg & 7;
  int xcd = bid & 7, loc = bid >> 3;
  int nb = (xcd < r8 ? xcd * (q8 + 1) : r8 * (q8 + 1) + (xcd - r8) * q8) + loc;
  int bn = nb % gridDim.x, bm = nb / gridDim.x;
  int m0 = bm * 128, n0 = bn * 128;
  int tid = threadIdx.x, wave = tid >> 6, lane = tid & 63;
  int wm = (wave >> 1) * 64, wn = (wave & 1) * 64;
  int lm = lane & 15, lk = (lane >> 4) * 8;
  int lr = lane >> 3;                  // row within 8-row chunk
  int cse = ((lane & 7) ^ lr) * 8;     // pre-swizzled source slot
  f32x4 acc[4][4] = {};

  int NT = K / 64;
  for (int t = 0; t < NT; ++t) {
    #pragma unroll
    for (int i = 0; i < 4; ++i) {
      int row = (wave * 4 + i) * 8;    // 16 chunks of 8 rows; 4 per wave
      async16(A + (size_t)(m0 + row + lr) * lda + t * 64 + cse, &As[row * 64]);
      async16(W + (size_t)(n0 + row + lr) * ldw + t * 64 + cse, &Bs[row * 64]);
    }
    WAITV(0);
    BAR();
    #pragma unroll
    for (int ks = 0; ks < 64; ks += 32) {
      bf16x8 af[4], bf[4];
      #pragma unroll
      for (int i = 0; i < 4; ++i) {
        int row = wm + i * 16 + lm;
        af[i] = *(const bf16x8*)&As[row * 64 + ((((ks + lk) >> 3) ^ (row & 7)) << 3)];
      }
      #pragma unroll
      for (int j = 0; j < 4; ++j) {
        int row = wn + j * 16 + lm;
        bf[j] = *(const bf16x8*)&Bs[row * 64 + ((((ks + lk) >> 3) ^ (row & 7)) << 3)];
      }
      #pragma unroll
      for (int i = 0; i < 4; ++i)
        #pragma unroll
        for (int j = 0; j < 4; ++j)
          acc[i][j] = __builtin_amdgcn_mfma_f32_16x16x32_bf16(af[i], bf[j], acc[i][j], 0, 0, 0);
    }
    BAR();
  }
  // ---- epilogue
  int r0 = m0 + wm + (lane >> 4) * 4;
  #pragma unroll
  for (int i = 0; i < 4; ++i) {
    #pragma unroll
    for (int j = 0; j < 4; ++j) {
      int col = n0 + wn + j * 16 + lm;
      if (col < N) {
        #pragma unroll
        for (int r = 0; r < 4; ++r) {
          int row = r0 + i * 16 + r;
          size_t idx = (size_t)row * ldc + col;
          float v = acc[i][j][r];
          if (resid) v += resid[idx];
          if (OUT_F32) ((float*)Cout)[idx] = v;
          else         ((bf16*)Cout)[idx]  = (bf16)v;
        }
      }
    }
  }
}

// ---------------------------------------------------------------- conv1d+SiLU (B/C cols only)
__global__ __launch_bounds__(256) void conv_bc_kernel(
    const bf16* __restrict__ xbcdt, const float* __restrict__ cw,
    const float* __restrict__ cb, bf16* __restrict__ xc) {
  int idx = blockIdx.x * 256 + threadIdx.x;
  if (idx >= BL_ * 16) return;          // 128 B/C cols / 8
  int c8 = idx & 15, t = idx >> 4;
  int l = t % L_;
  int c = DI_ + c8 * 8;
  float acc[8];
  f32x4 bv0 = *(const f32x4*)(cb + c);
  f32x4 bv1 = *(const f32x4*)(cb + c + 4);
  #pragma unroll
  for (int q = 0; q < 4; q++) { acc[q] = bv0[q]; acc[4 + q] = bv1[q]; }
  #pragma unroll
  for (int k = 0; k < 4; k++) {
    int ls = l + k - 3;
    if (ls >= 0) {
      const bf16* xp = xbcdt + (size_t)(t + k - 3) * XBCD_ + c;
      bf16x8 xv = *(const bf16x8*)xp;
      f32x4 wv0 = *(const f32x4*)(cw + k * CONV_ + c);
      f32x4 wv1 = *(const f32x4*)(cw + k * CONV_ + c + 4);
      #pragma unroll
      for (int q = 0; q < 4; q++) { acc[q] += (float)xv[q] * wv0[q]; acc[4 + q] += (float)xv[4 + q] * wv1[q]; }
    }
  }
  bf16x8 o;
  #pragma unroll
  for (int q = 0; q < 8; q++) o[q] = (bf16)silu_f(acc[q]);
  *(bf16x8*)(xc + (size_t)t * CONV_ + c) = o;
}

// ---------------------------------------------------------------- dt (softplus)
__global__ __launch_bounds__(256) void dt_kernel(
    const bf16* __restrict__ xbcdt, const float* __restrict__ dt_bias,
    float* __restrict__ dtH) {
  int idx = blockIdx.x * 256 + threadIdx.x;
  if (idx >= BL_ * NH) return;
  int h = idx & 63, t = idx >> 6;
  float raw = (float)xbcdt[(size_t)t * XBCD_ + CONV_ + h] + dt_bias[h];
  float v = (raw > 20.f) ? raw : log1pf(expf(raw));
  dtH[(size_t)h * BL_ + t] = v;
}

// ---------------------------------------------------------------- Atot precompute
// Atot[b][h][c] = exp(-exp(A_log[h]) * sum_{i<64} dt[b, c*64+i, h]).
// Same serial summation order as the old state_scan (bit-identical).
__global__ __launch_bounds__(256) void atot_kernel(
    const float* __restrict__ dtH, const float* __restrict__ A_log,
    float* __restrict__ Atot) {
  int idx = blockIdx.x * 256 + threadIdx.x;
  if (idx >= B_ * NH * NCHUNK) return;
  int c = idx & 31, rem = idx >> 5;
  int h = rem & 63, b = rem >> 6;
  const float* p = dtH + (size_t)h * BL_ + b * L_ + c * 64;
  float s = 0.f;
  #pragma unroll 8
  for (int i = 0; i < 64; i++) s += p[i];
  Atot[idx] = expf(-expf(A_log[h]) * s);
}

// ---------------------------------------------------------------- scan pass 1 (MFMA SSD, fused x-conv)
// One block per (b,c,h). Convolves its own 64x64 x-sub-tile in registers
// (bit-identical to the old conv_silu path), stages into Xt, then the SSD
// chunk math. y(+Dx) overwrites the x-region of xc.
__global__ __launch_bounds__(256) void scan_chunk_mfma(
    bf16* __restrict__ xc, const bf16* __restrict__ xbcdt,
    const float* __restrict__ cw, const float* __restrict__ cb,
    const float* __restrict__ dtH,
    const float* __restrict__ A_log, const float* __restrict__ Dp,
    bf16* __restrict__ Sc) {
  __shared__ bf16 Bs[64][72];   // B rows s, cols n   (swizzled)
  __shared__ bf16 Cs[64][72];   // C rows t, cols n   (natural)
  __shared__ bf16 Xt[64][72];   // x^T rows p, cols s (swizzled)
  __shared__ bf16 Gh[64][72];   // masked G hi  [t][s], later wB hi [n][s]
  __shared__ bf16 Gl[64][72];   // masked G lo  [t][s], later wB lo [n][s]
  __shared__ float dts[64];
  __shared__ float cum[64];
  __shared__ float wsA[64];
  int bi = blockIdx.x;
  int h = bi & 63, c = (bi >> 6) & 31, b = bi >> 11;
  int tid = threadIdx.x;
  int wave = tid >> 6, lane = tid & 63;
  int lm = lane & 15, lk = (lane >> 4) * 8;
  int cl = lane & 15, rw4 = (lane >> 4) * 4;
  int wt = (wave >> 1) * 32, wq = (wave & 1) * 32;
  size_t rowbase = (size_t)b * L_ + c * 64;
  float aA = expf(A_log[h]);
  // ---- stage: x via fused conv (registers), B (swizzled), C (natural)
  #pragma unroll
  for (int i = 0; i < 2; i++) {
    int cc = tid + i * 256;
    int s = cc >> 3, e8 = (cc & 7) * 8;
    const bf16* base = xc + (rowbase + s) * CONV_;
    bf16x8 bv = *(const bf16x8*)(base + DI_ + e8);
    bf16x8 cv = *(const bf16x8*)(base + DI_ + NST + e8);
    *(bf16x8*)&Bs[s][e8 ^ (s & 56)] = bv;
    *(bf16x8*)&Cs[s][e8] = cv;
    // fused depthwise conv + SiLU for x columns h*PD + e8 .. +7
    int col = h * PD + e8;
    int l = c * 64 + s;
    float acc[8];
    f32x4 cb0 = *(const f32x4*)(cb + col);
    f32x4 cb1 = *(const f32x4*)(cb + col + 4);
    #pragma unroll
    for (int q = 0; q < 4; q++) { acc[q] = cb0[q]; acc[4 + q] = cb1[q]; }
    #pragma unroll
    for (int k = 0; k < 4; k++) {
      int ls = l + k - 3;
      if (ls >= 0) {
        const bf16* xp = xbcdt + (rowbase + s + k - 3) * XBCD_ + col;
        bf16x8 xv = *(const bf16x8*)xp;
        f32x4 wv0 = *(const f32x4*)(cw + k * CONV_ + col);
        f32x4 wv1 = *(const f32x4*)(cw + k * CONV_ + col + 4);
        #pragma unroll
        for (int q = 0; q < 4; q++) { acc[q] += (float)xv[q] * wv0[q]; acc[4 + q] += (float)xv[4 + q] * wv1[q]; }
      }
    }
    #pragma unroll
    for (int q = 0; q < 8; q++) Xt[e8 + q][s ^ e8] = (bf16)silu_f(acc[q]);
  }
  if (tid < 64) dts[tid] = dtH[(size_t)h * BL_ + rowbase + tid];
  __syncthreads();
  // ---- inclusive prefix sum of dt (wave 0)
  if (tid < 64) {
    float v = dts[tid];
    #pragma unroll
    for (int off = 1; off < 64; off <<= 1) {
      float o = __shfl_up(v, off, 64);
      if (tid >= off) v += o;
    }
    cum[tid] = v;
  }
  __syncthreads();
  if (tid < 64) wsA[tid] = expf(-aA * (cum[63] - cum[tid])) * dts[tid];
  // ---- G[t][s] = sum_n C[t][n] * B[s][n]
  f32x4 gacc[2][2] = {};
  #pragma unroll
  for (int ks = 0; ks < 64; ks += 32) {
    bf16x8 af[2], bfr[2];
    #pragma unroll
    for (int i = 0; i < 2; i++) af[i] = *(bf16x8*)&Cs[wt + i * 16 + lm][ks + lk];
    #pragma unroll
    for (int j = 0; j < 2; j++) {
      int S = wq + j * 16 + lm;
      bfr[j] = *(bf16x8*)&Bs[S][(ks + lk) ^ (S & 56)];
    }
    #pragma unroll
    for (int i = 0; i < 2; i++)
      #pragma unroll
      for (int j = 0; j < 2; j++)
        gacc[i][j] = __builtin_amdgcn_mfma_f32_16x16x32_bf16(af[i], bfr[j], gacc[i][j], 0, 0, 0);
  }
  // ---- causal decay mask, hi/lo split -> Gh/Gl [t][s]
  #pragma unroll
  for (int i = 0; i < 2; i++) {
    #pragma unroll
    for (int j = 0; j < 2; j++) {
      #pragma unroll
      for (int r = 0; r < 4; r++) {
        int t = wt + i * 16 + rw4 + r;
        int s = wq + j * 16 + cl;
        float g = 0.f;
        if (s <= t) g = gacc[i][j][r] * expf(-aA * (cum[t] - cum[s])) * dts[s];
        bf16 ghi = (bf16)g;
        Gh[t][s] = ghi;
        Gl[t][s] = (bf16)(g - (float)ghi);
      }
    }
  }
  __syncthreads();
  // ---- Y[t][p] = sum_s Gm[t][s] * x_s[p];  + D*x; write into xc x-region
  f32x4 yacc[2][2] = {};
  #pragma unroll
  for (int ks = 0; ks < 64; ks += 32) {
    bf16x8 ah[2], al[2], bx[2];
    #pragma unroll
    for (int i = 0; i < 2; i++) {
      ah[i] = *(bf16x8*)&Gh[wt + i * 16 + lm][ks + lk];
      al[i] = *(bf16x8*)&Gl[wt + i * 16 + lm][ks + lk];
    }
    #pragma unroll
    for (int j = 0; j < 2; j++) {
      int P = wq + j * 16 + lm;
      bx[j] = *(bf16x8*)&Xt[P][(ks + lk) ^ (P & 56)];
    }
    #pragma unroll
    for (int i = 0; i < 2; i++)
      #pragma unroll
      for (int j = 0; j < 2; j++) {
        yacc[i][j] = __builtin_amdgcn_mfma_f32_16x16x32_bf16(ah[i], bx[j], yacc[i][j], 0, 0, 0);
        yacc[i][j] = __builtin_amdgcn_mfma_f32_16x16x32_bf16(al[i], bx[j], yacc[i][j], 0, 0, 0);
      }
  }
  float Dv = Dp[h];
  #pragma unroll
  for (int i = 0; i < 2; i++) {
    #pragma unroll
    for (int j = 0; j < 2; j++) {
      int p = wq + j * 16 + cl;
      #pragma unroll
      for (int r = 0; r < 4; r++) {
        int t = wt + i * 16 + rw4 + r;
        float yv = yacc[i][j][r] + Dv * (float)Xt[p][t ^ (p & 56)];
        xc[(rowbase + t) * CONV_ + h * PD + p] = (bf16)yv;
      }
    }
  }
  __syncthreads();
  // ---- wB[n][s] = w_s * B_s[n], hi/lo into Gh/Gl (reuse buffers)
  #pragma unroll
  for (int i = 0; i < 2; i++) {
    int cc = tid + i * 256;
    int n = cc >> 3, s8 = (cc & 7) * 8;
    bf16x8 vh, vl;
    #pragma unroll
    for (int q = 0; q < 8; q++) {
      int s = s8 + q;
      float wb = (float)Bs[s][n ^ (s & 56)] * wsA[s];
      vh[q] = (bf16)wb;
      vl[q] = (bf16)(wb - (float)vh[q]);
    }
    *(bf16x8*)&Gh[n][s8] = vh;
    *(bf16x8*)&Gl[n][s8] = vl;
  }
  __syncthreads();
  // ---- S[p][n] = sum_s x_s[p] * wB[n][s]; write Sc
  f32x4 sacc[2][2] = {};
  #pragma unroll
  for (int ks = 0; ks < 64; ks += 32) {
    bf16x8 ax[2], bh[2], bl[2];
    #pragma unroll
    for (int i = 0; i < 2; i++) {
      int P = wt + i * 16 + lm;
      ax[i] = *(bf16x8*)&Xt[P][(ks + lk) ^ (P & 56)];
    }
    #pragma unroll
    for (int j = 0; j < 2; j++) {
      bh[j] = *(bf16x8*)&Gh[wq + j * 16 + lm][ks + lk];
      bl[j] = *(bf16x8*)&Gl[wq + j * 16 + lm][ks + lk];
    }
    #pragma unroll
    for (int i = 0; i < 2; i++)
      #pragma unroll
      for (int j = 0; j < 2; j++) {
        sacc[i][j] = __builtin_amdgcn_mfma_f32_16x16x32_bf16(ax[i], bh[j], sacc[i][j], 0, 0, 0);
        sacc[i][j] = __builtin_amdgcn_mfma_f32_16x16x32_bf16(ax[i], bl[j], sacc[i][j], 0, 0, 0);
      }
  }
  bf16* scp = Sc + ((((size_t)b * NCHUNK + c) * NH + h) << 12);
  #pragma unroll
  for (int i = 0; i < 2; i++) {
    #pragma unroll
    for (int j = 0; j < 2; j++) {
      int n = wq + j * 16 + cl;
      #pragma unroll
      for (int r = 0; r < 4; r++) {
        int p = wt + i * 16 + rw4 + r;
        scp[p * 64 + n] = (bf16)sacc[i][j][r];
      }
    }
  }
}

// ---------------------------------------------------------------- scan pass 2 (element-parallel)
// 2048 blocks; each thread owns one (p,n) element of one (b,h) and walks the
// 32 chunks serially: o_c = H; H = Atot[c]*H + S_c. In-place h_prev rewrite.
__global__ __launch_bounds__(256) void state_scan_kernel(
    bf16* __restrict__ Sc, const float* __restrict__ Atot) {
  __shared__ float At[NCHUNK];
  int bid = blockIdx.x;
  int seg = bid & 15, rem = bid >> 4;          // rem = b*64 + h
  int e = seg * 256 + threadIdx.x;             // element in [0,4096)
  if (threadIdx.x < NCHUNK) At[threadIdx.x] = Atot[(rem << 5) + threadIdx.x];
  __syncthreads();
  int h = rem & 63, b = rem >> 6;
  bf16* p = Sc + ((((size_t)b * NCHUNK) * NH + h) << 12) + e;
  const size_t cstride = (size_t)NH << 12;
  float H = 0.f;
  #pragma unroll 4
  for (int c = 0; c < NCHUNK; ++c) {
    float s = (float)*p;
    *p = (bf16)H;                              // h_prev for chunk c
    H = At[c] * H + s;
    p += cstride;
  }
}

// ---------------------------------------------------------------- scan pass 3 (MFMA)
__global__ __launch_bounds__(256) void y_inter_mfma(
    bf16* __restrict__ xc, const float* __restrict__ dtH,
    const float* __restrict__ A_log, const bf16* __restrict__ Sc) {
  __shared__ bf16 Cs[64][72];
  __shared__ bf16 Hs[64][72];
  __shared__ float dts[64];
  __shared__ float eA[64];
  int bi = blockIdx.x;
  int h = bi & 63, c = (bi >> 6) & 31, b = bi >> 11;
  int tid = threadIdx.x;
  int wave = tid >> 6, lane = tid & 63;
  int lm = lane & 15, lk = (lane >> 4) * 8;
  int cl = lane & 15, rw4 = (lane >> 4) * 4;
  int wt = (wave >> 1) * 32, wp = (wave & 1) * 32;
  size_t rowbase = (size_t)b * L_ + c * 64;
  float aA = expf(A_log[h]);
  const bf16* scp = Sc + ((((size_t)b * NCHUNK + c) * NH + h) << 12);
  #pragma unroll
  for (int i = 0; i < 2; i++) {
    int cc = tid + i * 256;
    int s = cc >> 3, e8 = (cc & 7) * 8;
    bf16x8 cv = *(const bf16x8*)(xc + (rowbase + s) * CONV_ + DI_ + NST + e8);
    *(bf16x8*)&Cs[s][e8] = cv;
  }
  {
    int p = tid >> 2, n16 = (tid & 3) * 16;
    *(bf16x8*)&Hs[p][n16]     = *(const bf16x8*)(scp + p * 64 + n16);
    *(bf16x8*)&Hs[p][n16 + 8] = *(const bf16x8*)(scp + p * 64 + n16 + 8);
  }
  if (tid < 64) dts[tid] = dtH[(size_t)h * BL_ + rowbase + tid];
  __syncthreads();
  if (tid < 64) {
    float v = dts[tid];
    #pragma unroll
    for (int off = 1; off < 64; off <<= 1) {
      float o = __shfl_up(v, off, 64);
      if (tid >= off) v += o;
    }
    eA[tid] = expf(-aA * v);
  }
  __syncthreads();
  f32x4 acc[2][2] = {};
  #pragma unroll
  for (int ks = 0; ks < 64; ks += 32) {
    bf16x8 af[2], bfr[2];
    #pragma unroll
    for (int i = 0; i < 2; i++) af[i]  = *(bf16x8*)&Cs[wt + i * 16 + lm][ks + lk];
    #pragma unroll
    for (int j = 0; j < 2; j++) bfr[j] = *(bf16x8*)&Hs[wp + j * 16 + lm][ks + lk];
    #pragma unroll
    for (int i = 0; i < 2; i++)
      #pragma unroll
      for (int j = 0; j < 2; j++)
        acc[i][j] = __builtin_amdgcn_mfma_f32_16x16x32_bf16(af[i], bfr[j], acc[i][j], 0, 0, 0);
  }
  #pragma unroll
  for (int i = 0; i < 2; i++) {
    #pragma unroll
    for (int j = 0; j < 2; j++) {
      int p = wp + j * 16 + cl;
      #pragma unroll
      for (int r = 0; r < 4; r++) {
        int t = wt + i * 16 + rw4 + r;
        size_t gi = (rowbase + t) * CONV_ + h * PD + p;
        xc[gi] = (bf16)((float)xc[gi] + eA[t] * acc[i][j][r]);
      }
    }
  }
}

// ---------------------------------------------------------------- gated RMSNorm
__global__ __launch_bounds__(256) void gated_norm_kernel(
    const bf16* __restrict__ xc, bf16* __restrict__ zbuf,
    const float* __restrict__ nw) {
  int t = blockIdx.x;
  int base = threadIdx.x * 16;
  const bf16* yr = xc + (size_t)t * CONV_;
  bf16* zr = zbuf + (size_t)t * DI_;
  float tv[16], ss = 0.f;
  #pragma unroll
  for (int i8 = 0; i8 < 2; i8++) {
    bf16x8 yv = *(const bf16x8*)(yr + base + i8 * 8);
    bf16x8 zv = *(const bf16x8*)(zr + base + i8 * 8);
    #pragma unroll
    for (int q = 0; q < 8; q++) {
      float tt = (float)yv[q] * silu_f((float)zv[q]);
      tv[i8 * 8 + q] = tt;
      ss += tt * tt;
    }
  }
  ss = block_reduce_sum_256(ss);
  float r = rsqrtf(ss / (float)DI_ + EPS_);
  #pragma unroll
  for (int i8 = 0; i8 < 2; i8++) {
    f32x4 w0 = *(const f32x4*)(nw + base + i8 * 8);
    f32x4 w1 = *(const f32x4*)(nw + base + i8 * 8 + 4);
    bf16x8 o;
    #pragma unroll
    for (int q = 0; q < 4; q++) {
      o[q]     = (bf16)(w0[q] * tv[i8 * 8 + q] * r);
      o[4 + q] = (bf16)(w1[q] * tv[i8 * 8 + 4 + q] * r);
    }
    *(bf16x8*)(zr + base + i8 * 8) = o;
  }
}

// ---------------------------------------------------------------- ws diagnostic
__global__ void ws_report_kernel(float* out, float ws_mb) {
  if (blockIdx.x == 0 && threadIdx.x == 0) out[0] = ws_mb;
}

// ---------------------------------------------------------------- launch
extern "C" void kernel_launch(void* const* d_in, const int* in_sizes, int n_in,
                              void* d_out, int out_size, void* d_ws, size_t ws_size,
                              hipStream_t stream) {
  const float* u        = (const float*)d_in[0];
  const float* ln_w     = (const float*)d_in[1];
  const float* in_proj  = (const float*)d_in[2];
  const float* conv_w   = (const float*)d_in[3];
  const float* conv_b   = (const float*)d_in[4];
  const float* dt_bias  = (const float*)d_in[5];
  const float* A_log    = (const float*)d_in[6];
  const float* Dp       = (const float*)d_in[7];
  const float* norm_w   = (const float*)d_in[8];
  const float* out_proj = (const float*)d_in[9];
  float* out = (float*)d_out;

  bf16* hs = (bf16*)d_out;     // scratch inside d_out (dead before final GEMM)

  char* ws = (char*)d_ws;
  size_t off = 0;
  auto alloc = [&](size_t bytes) { char* p = ws + off; off = (off + bytes + 255) & ~(size_t)255; return p; };
  float* dtH  = (float*)alloc((size_t)BL_ * NH * 4);          //  1.05 MB  [h][b*L+t]
  float* Atot = (float*)alloc((size_t)B_ * NH * NCHUNK * 4);  //  16 KB
  bf16*  wbuf = (bf16*)alloc((size_t)4352 * DM_ * 2);         // 17.8 MB bf16 weight slice
  bf16*  shbuf= (bf16*)alloc((size_t)BL_ * XBCD_ * 2);        // 35.1 MB (xbcdt → zbuf)
  bf16*  xc   = (bf16*)alloc((size_t)BL_ * CONV_ * 2);        // 34.6 MB
  bf16*  Sc   = (bf16*)alloc((size_t)B_ * NCHUNK * NH * 64 * 64 * 2);  // 32 MB
  size_t need = off;                                          // ~120.6 MB

  if (ws_size < need) {
    ws_report_kernel<<<1, 64, 0, stream>>>(out, (float)(ws_size >> 20));
    return;
  }

  bf16* xbcdt = shbuf;          // phase 1: BL x XBCD_  (live through scan pass 1)
  bf16* zbuf  = shbuf;          // phase 3: BL x DI_

  rmsnorm_in_kernel<<<BL_, 256, 0, stream>>>(u, ln_w, hs);

  // GEMM1: zxbcdt tail (xBC + dt), weights padded to 4352 rows.
  {
    long nsrc = (long)XBCD_ * DM_, ndst = (long)4352 * DM_;
    convert_w_kernel<<<(int)(ndst / 8 / 256), 256, 0, stream>>>(
        in_proj + (size_t)DI_ * DM_, wbuf, nsrc, ndst);
    gemm_nt_sb<false><<<dim3(4352 / 128, BL_ / 128), 256, 0, stream>>>(
        hs, DM_, wbuf, DM_, xbcdt, XBCD_, nullptr, XBCD_, DM_);
  }
  conv_bc_kernel<<<(BL_ * 16 + 255) / 256, 256, 0, stream>>>(
      xbcdt, conv_w, conv_b, xc);
  dt_kernel<<<(BL_ * NH + 255) / 256, 256, 0, stream>>>(
      xbcdt, dt_bias, dtH);
  atot_kernel<<<(B_ * NH * NCHUNK + 255) / 256, 256, 0, stream>>>(
      dtH, A_log, Atot);
  // chunked SSD scan with fused x-conv (xbcdt still live)
  scan_chunk_mfma<<<B_ * NH * NCHUNK, 256, 0, stream>>>(
      xc, xbcdt, conv_w, conv_b, dtH, A_log, Dp, Sc);
  state_scan_kernel<<<B_ * NH * 16, 256, 0, stream>>>(Sc, Atot);
  y_inter_mfma<<<B_ * NH * NCHUNK, 256, 0, stream>>>(xc, dtH, A_log, Sc);

  // GEMM2: z part of in_proj (xbcdt dead; shbuf becomes zbuf)
  {
    long n = (long)DI_ * DM_;
    convert_w_kernel<<<(int)(n / 8 / 256), 256, 0, stream>>>(in_proj, wbuf, n, n);
    gemm_nt_sb<false><<<dim3(DI_ / 128, BL_ / 128), 256, 0, stream>>>(
        hs, DM_, wbuf, DM_, zbuf, DI_, nullptr, DI_, DM_);
  }
  gated_norm_kernel<<<BL_, 256, 0, stream>>>(xc, zbuf, norm_w);

  // GEMM3: out projection + residual
  {
    long n = (long)DM_ * DI_;
    convert_w_kernel<<<(int)(n / 8 / 256), 256, 0, stream>>>(out_proj, wbuf, n, n);
    gemm_nt_sb<true><<<dim3(DM_ / 128, BL_ / 128), 256, 0, stream>>>(
        zbuf, DI_, wbuf, DI_, out, DM_, u, DM_, DI_);
  }
}